// Round 1
// 89.315 us; speedup vs baseline: 1.0032x; 1.0032x over previous
//
#include <hip/hip_runtime.h>
#include <math.h>

#define BB 16
#define TD 1024
#define HD 512
#define UD 600
#define AD 80
#define KG 10
#define PC 30      // 3*K

#define LOG2E 1.4426950408889634f

#if __has_builtin(__builtin_amdgcn_exp2f)
#define EXP2F(x) __builtin_amdgcn_exp2f(x)
#else
#define EXP2F(x) exp2f(x)
#endif

typedef short v8s __attribute__((ext_vector_type(8)));
typedef float v4f __attribute__((ext_vector_type(4)));

__device__ inline unsigned short f2bf(float f) {            // RNE fp32->bf16
    unsigned u = __float_as_uint(f);
    return (unsigned short)((u + 0x7FFF + ((u >> 16) & 1)) >> 16);
}

// ======== single fused kernel: params GEMM (MFMA split-bf16, W fragments
// ======== gathered+converted in-register from the L2-hot 60KB W) + exp +
// ======== gaussian window + btu,bua->bta einsum =====
// 512 blocks x 320 thr (5 waves); block = (batch b, 32 t's).
// Phase A: waves 0-3 compute the 32x512 @ 512x32 params GEMM; wave wv owns
//   k in [128wv, 128wv+128) = 4 ktiles; 2 Mtiles x 2 Ntiles; 3 MFMA passes
//   (hh, lh, hl) ~= fp32 accuracy (R5-verified path, absmax unchanged).
//   B-fragment for mfma_f32_16x16x32_bf16: B[k=(lane>>4)*8+j][n=lane&15],
//   i.e. lane (quad,m), pass n reads W[(g*32+quad*8+j)*30 + n*16+m], c>=30
//   zero-padded. Gather spans 4 rows x 64B contiguous per load -> L1-hot.
// Phase B: 4 partials reduced in LDS + exp transform -> params_l.
// Phase C: dynamic u-range (skip chunks where every term < 2^-46*max(a,1);
//   abs err < 1e-9 for ANY input, graceful full-loop fallback) + einsum.
#define TT 32     // t-tile per block
#define UC 40     // u chunk
#define NCHUNK 15 // 600/40
#define NTHR 320  // 5 waves

__global__ __launch_bounds__(NTHR) void k_fused(const float* __restrict__ x,
                                                const float* __restrict__ W,
                                                const float* __restrict__ bias,
                                                const float* __restrict__ cs,
                                                float* __restrict__ out) {
    __shared__ float red[4 * TT * 33];    // [wv][row32][col33] 16896 B
    __shared__ float params_l[TT * 36];   // pitch 36
    __shared__ float cs_l[UC * AD];       // [u][a] pitch 80
    __shared__ float phi2[TT * 44];       // [t][u] pitch 44: b128 write+read
    __shared__ float range_l[2];

    int tid = threadIdx.x;
    int b = blockIdx.y;
    int t0 = blockIdx.x * TT;
    long r0 = (long)b * TD + t0;          // first global row of this tile

    int wv = tid >> 6;                    // 0..4
    int l = tid & 63;
    int quad = l >> 4, m = l & 15;

    // ================= Phase A: params GEMM (waves 0-3) =================
    if (wv < 4) {
        v4f acc[2][2];
        #pragma unroll
        for (int mt = 0; mt < 2; mt++)
            #pragma unroll
            for (int n = 0; n < 2; n++)
                acc[mt][n] = (v4f){0.f, 0.f, 0.f, 0.f};

        #pragma unroll
        for (int kt = 0; kt < 4; kt++) {
            int g = wv * 4 + kt;          // global ktile 0..15
            v8s ah[2], al[2];
            #pragma unroll
            for (int mt = 0; mt < 2; mt++) {
                const float* xr = x + (r0 + mt * 16 + m) * HD + g * 32 + quad * 8;
                float4 xa = *(const float4*)(xr);
                float4 xb = *(const float4*)(xr + 4);
                float xf[8] = {xa.x, xa.y, xa.z, xa.w, xb.x, xb.y, xb.z, xb.w};
                #pragma unroll
                for (int j = 0; j < 8; j++) {
                    unsigned short h = f2bf(xf[j]);
                    ah[mt][j] = (short)h;
                    al[mt][j] = (short)f2bf(xf[j] - __uint_as_float(((unsigned)h) << 16));
                }
            }
            #pragma unroll
            for (int n = 0; n < 2; n++) {
                // build B-fragments (hi/lo split) in-register from W
                int c = n * 16 + m;
                const float* wp = W + (g * 32 + quad * 8) * PC + c;
                bool ok = (c < PC);
                v8s bh, bl;
                #pragma unroll
                for (int j = 0; j < 8; j++) {
                    float v = ok ? wp[j * PC] : 0.f;
                    unsigned short h = f2bf(v);
                    bh[j] = (short)h;
                    bl[j] = (short)f2bf(v - __uint_as_float(((unsigned)h) << 16));
                }
                #pragma unroll
                for (int mt = 0; mt < 2; mt++) {
                    acc[mt][n] = __builtin_amdgcn_mfma_f32_16x16x32_bf16(ah[mt], bh, acc[mt][n], 0, 0, 0);
                    acc[mt][n] = __builtin_amdgcn_mfma_f32_16x16x32_bf16(al[mt], bh, acc[mt][n], 0, 0, 0);
                    acc[mt][n] = __builtin_amdgcn_mfma_f32_16x16x32_bf16(ah[mt], bl, acc[mt][n], 0, 0, 0);
                }
            }
        }

        // C/D layout: row = quad*4 + reg (+ mt*16), col = lane&15 (+ n*16)
        #pragma unroll
        for (int mt = 0; mt < 2; mt++)
            #pragma unroll
            for (int n = 0; n < 2; n++)
                #pragma unroll
                for (int r = 0; r < 4; r++)
                    red[wv * (TT * 33) + (mt * 16 + quad * 4 + r) * 33 + n * 16 + m]
                        = acc[mt][n][r];
    }
    __syncthreads();

    // ================= Phase B: reduce + exp transform ==================
    // params_l[t][c]: c 0..9 a=exp(p); 10..19 nb=-exp(p)*log2e; 20..29 k=exp(p)
    for (int idx = tid; idx < TT * PC; idx += NTHR) {
        int r = idx / PC, c = idx - r * PC;
        float s = red[0 * (TT * 33) + r * 33 + c] + red[1 * (TT * 33) + r * 33 + c]
                + red[2 * (TT * 33) + r * 33 + c] + red[3 * (TT * 33) + r * 33 + c];
        float e = __expf(s + bias[c]);
        params_l[r * 36 + c] = (c >= 10 && c < 20) ? (-e * LOG2E) : e;
    }
    __syncthreads();

    // ================= Phase C: gaussian window + einsum ================
    int tt = tid & 31;
    int sub = tid >> 5;                   // 0..9
    float pa[KG], pnb[KG], pk[KG];
    #pragma unroll
    for (int q = 0; q < KG; q++) {
        pa[q]  = params_l[tt * 36 + q];
        pnb[q] = params_l[tt * 36 + 10 + q];
        pk[q]  = params_l[tt * 36 + 20 + q];
    }

    // dynamic contributing u-range; wave 0 reduces (its 64 lanes cover all t)
    {
        float lo = 1e30f, hi = -1e30f;
        #pragma unroll
        for (int q = 0; q < KG; q++) {
            float bits = 46.f + fmaxf(0.f, __log2f(pa[q]));
            float w = __fsqrt_rn(bits / (-pnb[q]));   // pnb<0 strictly
            lo = fminf(lo, pk[q] - w);
            hi = fmaxf(hi, pk[q] + w);
        }
        if (tid < 64) {
            #pragma unroll
            for (int mk = 1; mk < 64; mk <<= 1) {
                lo = fminf(lo, __shfl_xor(lo, mk));
                hi = fmaxf(hi, __shfl_xor(hi, mk));
            }
            if (tid == 0) { range_l[0] = lo; range_l[1] = hi; }
        }
    }
    __syncthreads();
    float lo_m = fminf(fmaxf(range_l[0], 0.f), (float)(UD - 1));
    float hi_m = fminf(fmaxf(range_l[1], 0.f), (float)(UD - 1));
    int ch_lo = (int)lo_m / UC;
    int ch_hi = (int)hi_m / UC;
    if (ch_lo > ch_hi) ch_lo = ch_hi;

    // einsum role: thread owns t-pair ty*2, a-quad tx*4
    int tx = tid % 20;   // 0..19
    int ty = tid / 20;   // 0..15
    float4 acc0 = {0.f, 0.f, 0.f, 0.f};
    float4 acc1 = {0.f, 0.f, 0.f, 0.f};

    const float* csb = cs + (long)b * UD * AD;

    for (int ch = ch_lo; ch <= ch_hi; ch++) {
        int u0 = ch * UC;
        __syncthreads();   // protect cs_l/phi2 from previous chunk's readers

        // stage char_seq chunk: 3200 floats = 800 float4, coalesced
        for (int idx = tid; idx < (UC * AD) / 4; idx += NTHR) {
            *(float4*)&cs_l[idx * 4] = *(const float4*)&csb[u0 * AD + idx * 4];
        }

        // compute phi for my t, my 4 u's; one b128 LDS write
        float ph[4];
        #pragma unroll
        for (int i = 0; i < 4; i++) {
            float uf = (float)(u0 + sub * 4 + i);
            float ss = 0.f;
            #pragma unroll
            for (int q = 0; q < KG; q++) {
                float d = uf - pk[q];
                ss += pa[q] * EXP2F(pnb[q] * d * d);
            }
            ph[i] = ss;
        }
        *(float4*)&phi2[tt * 44 + sub * 4] = make_float4(ph[0], ph[1], ph[2], ph[3]);
        __syncthreads();

        // einsum: out[t][a] += phi[t][u] * cs[u][a]; b128 phi + b128 cs
        #pragma unroll 2
        for (int g = 0; g < 10; g++) {
            float4 p0 = *(const float4*)&phi2[(ty * 2) * 44 + g * 4];
            float4 p1 = *(const float4*)&phi2[(ty * 2 + 1) * 44 + g * 4];
            #pragma unroll
            for (int i = 0; i < 4; i++) {
                float4 c4 = *(const float4*)&cs_l[(g * 4 + i) * AD + tx * 4];
                float pi0 = (i == 0) ? p0.x : (i == 1) ? p0.y : (i == 2) ? p0.z : p0.w;
                float pi1 = (i == 0) ? p1.x : (i == 1) ? p1.y : (i == 2) ? p1.z : p1.w;
                acc0.x += pi0 * c4.x; acc0.y += pi0 * c4.y;
                acc0.z += pi0 * c4.z; acc0.w += pi0 * c4.w;
                acc1.x += pi1 * c4.x; acc1.y += pi1 * c4.y;
                acc1.z += pi1 * c4.z; acc1.w += pi1 * c4.w;
            }
        }
    }

    // store 2 t-rows x 4 a's
    long t = r0 + ty * 2;
    *(float4*)(out + t * AD + tx * 4) = acc0;
    *(float4*)(out + (t + 1) * AD + tx * 4) = acc1;
}

extern "C" void kernel_launch(void* const* d_in, const int* in_sizes, int n_in,
                              void* d_out, int out_size, void* d_ws, size_t ws_size,
                              hipStream_t stream) {
    const float* lstm = (const float*)d_in[0];   // [16,1024,512]
    const float* cs   = (const float*)d_in[1];   // [16,600,80]
    const float* W    = (const float*)d_in[2];   // [512,30]
    const float* bias = (const float*)d_in[3];   // [30]
    float* out = (float*)d_out;                  // [16,1024,80]

    (void)d_ws; (void)ws_size;                   // workspace no longer needed

    dim3 grid(TD / TT, BB);
    k_fused<<<grid, NTHR, 0, stream>>>(lstm, W, bias, cs, out);
}